// Round 1
// baseline (413.271 us; speedup 1.0000x reference)
//
#include <hip/hip_runtime.h>
#include <stdint.h>

// ---------------------------------------------------------------------------
// Char segmentation loss.
// d_out layout: [0]=loss_low, [1]=loss_middle, [2..2+512*27*1024)=mask_low (f32 0/1)
// One block per batch element per resolution branch. Memory-bound kernel:
// ~300 MB read + 57 MB write -> ~57 us floor at 6.3 TB/s.
// ---------------------------------------------------------------------------

static __device__ __forceinline__ float wave_reduce_add(float v) {
  v += __shfl_xor(v, 1, 64);
  v += __shfl_xor(v, 2, 64);
  v += __shfl_xor(v, 4, 64);
  v += __shfl_xor(v, 8, 64);
  v += __shfl_xor(v, 16, 64);
  v += __shfl_xor(v, 32, 64);
  return v;
}

__global__ void zero_kernel(float* out) {
  if (threadIdx.x < 2) out[threadIdx.x] = 0.0f;
}

// LOW: char_feature_low [512,27,16,64], writes mask_low, accumulates out[0]
// !LOW (mid): char_feature_mid [512,27,32,128], accumulates out[1]
template <bool LOW>
__global__ __launch_bounds__(256) void loss_kernel(
    const float* __restrict__ cf,     // [512,27,HW]
    const float* __restrict__ attn,   // [512,26,32]
    const float* __restrict__ fore,   // [512,1,32,128]
    const int* __restrict__ length,   // [512]
    const float* __restrict__ alpha_p,
    float* __restrict__ out) {
  constexpr int W  = LOW ? 64 : 128;
  constexpr int HW = LOW ? 1024 : 4096;
  constexpr int PX = HW / 256;

  const int b = blockIdx.x;
  const int t = threadIdx.x;

  __shared__ float    sattn[26 * 32];
  __shared__ uint32_t sbits[W];
  __shared__ float    red[4][82];  // [wave][inter 0..26 | s1 27..53 | s2 54..80 | ce 81]

  // Stage attn[b] into LDS (coalesced).
  for (int i = t; i < 26 * 32; i += 256) sattn[i] = attn[b * 832 + i];
  __syncthreads();

  const float alpha = alpha_p[0];
  const int lens = length[b] - 1;  // attn channels 0..lens-1 kept

  // Per-column thresholded attention bits, replicating jax.image.resize
  // half-pixel bilinear (antialias=False). Edge renorm == clamp-to-edge.
  if (t < W) {
    const float src = (LOW ? 0.5f : 0.25f) * (float)t - (LOW ? 0.25f : 0.375f);
    const int k0 = (int)floorf(src);
    const float frac = src - (float)k0;  // exact (multiples of 1/8)
    uint32_t bits = 0u;
    if (k0 < 0 || k0 >= 31) {
      const int kk = (k0 < 0) ? 0 : 31;
      for (int c = 0; c < 26; ++c) {
        float v = (c < lens) ? sattn[c * 32 + kk] : 0.0f;
        if (v > alpha) bits |= (1u << c);
      }
    } else {
      const float w1 = frac, w0 = 1.0f - frac;
      for (int c = 0; c < 26; ++c) {
        // __f*_rn: forbid fma contraction so we bit-match the reference dot.
        float v = __fadd_rn(__fmul_rn(w0, sattn[c * 32 + k0]),
                            __fmul_rn(w1, sattn[c * 32 + k0 + 1]));
        v = (c < lens) ? v : 0.0f;
        if (v > alpha) bits |= (1u << c);
      }
    }
    sbits[t] = bits;
  }
  __syncthreads();

  float inter[27], s1[27], s2[27];
#pragma unroll
  for (int c = 0; c < 27; ++c) { inter[c] = 0.0f; s1[c] = 0.0f; s2[c] = 0.0f; }
  float ce = 0.0f;

  const float* cfb = cf + (size_t)b * 27 * HW;
  float* mout = out + 2 + (size_t)b * 27 * 1024;  // mask_low region (LOW only)

  for (int k = 0; k < PX; ++k) {
    const int p = t + k * 256;
    const int x = p & (W - 1);

    int fmw;
    if (LOW) {
      // fm_low = (4-tap half-pixel average of fore_mask >= 0.4)
      const int y = p >> 6;
      const float2* fr =
          (const float2*)(fore + (size_t)b * 4096 + (size_t)(2 * y) * 128 + 2 * x);
      const float2 f0 = fr[0];
      const float2 f1 = fr[64];  // next row (+128 floats)
      const float t0 = __fadd_rn(0.5f * f0.x, 0.5f * f1.x);
      const float t1 = __fadd_rn(0.5f * f0.y, 0.5f * f1.y);
      const float fmv = __fadd_rn(0.5f * t0, 0.5f * t1);
      fmw = (fmv >= 0.4f) ? 1 : 0;
    } else {
      // Identity resize: fm_mid = fore_mask >= 0.4
      fmw = (fore[(size_t)b * 4096 + p] >= 0.4f) ? 1 : 0;
    }

    const uint32_t bits = sbits[x];
    const int target = fmw ? (int)__ffs(bits) : 0;  // first set bit -> channel idx

    float l[27];
    float m = -1e30f;
    float lt = 0.0f;
#pragma unroll
    for (int c = 0; c < 27; ++c) {
      const float v = cfb[(size_t)c * HW + p];
      l[c] = v;
      m = fmaxf(m, v);
      lt = (c == target) ? v : lt;
    }
    float s = 0.0f;
#pragma unroll
    for (int c = 0; c < 27; ++c) {
      const float e = __expf(l[c] - m);
      l[c] = e;
      s += e;
    }
    const float inv = 1.0f / s;
    const float logZ = m + __logf(s);
    ce += (logZ - lt);  // -log p(target)

#pragma unroll
    for (int c = 0; c < 27; ++c) {
      const float prob = l[c] * inv;
      s1[c] += prob;
      float mf;
      if (c == 0) {
        mf = (float)(1 - fmw);
      } else {
        mf = (float)(((bits >> (c - 1)) & 1u) & (uint32_t)fmw);
      }
      inter[c] += prob * mf;
      s2[c] += mf;
      if (LOW) mout[(size_t)c * 1024 + p] = mf;
    }
  }

  // Block reduction: butterfly within wave, then cross-wave via LDS.
  const int wave = t >> 6;
  const int lane = t & 63;
#pragma unroll
  for (int c = 0; c < 27; ++c) {
    inter[c] = wave_reduce_add(inter[c]);
    s1[c] = wave_reduce_add(s1[c]);
    s2[c] = wave_reduce_add(s2[c]);
  }
  ce = wave_reduce_add(ce);
  if (lane == 0) {
#pragma unroll
    for (int c = 0; c < 27; ++c) {
      red[wave][c] = inter[c];
      red[wave][27 + c] = s1[c];
      red[wave][54 + c] = s2[c];
    }
    red[wave][81] = ce;
  }
  __syncthreads();

  if (t == 0) {
    const float ces = red[0][81] + red[1][81] + red[2][81] + red[3][81];
    float dice = 0.0f;
    for (int c = 1; c < 27; ++c) {
      const float I  = red[0][c] + red[1][c] + red[2][c] + red[3][c];
      const float S1 = red[0][27 + c] + red[1][27 + c] + red[2][27 + c] + red[3][27 + c];
      const float S2 = red[0][54 + c] + red[1][54 + c] + red[2][54 + c] + red[3][54 + c];
      const float score = (2.0f * I + 1.0f) / (S1 + S2 + 1.0f);
      if (c <= lens) dice += (1.0f - score);
    }
    dice /= (float)lens;
    const float contrib =
        dice * (1.0f / 512.0f) + ces * (1.0f / (512.0f * (float)HW));
    atomicAdd(&out[LOW ? 0 : 1], contrib);
  }
}

extern "C" void kernel_launch(void* const* d_in, const int* in_sizes, int n_in,
                              void* d_out, int out_size, void* d_ws, size_t ws_size,
                              hipStream_t stream) {
  const float* cf_mid = (const float*)d_in[0];  // [512,27,32,128]
  const float* cf_low = (const float*)d_in[1];  // [512,27,16,64]
  const float* attn   = (const float*)d_in[2];  // [512,26,32]
  const float* fore   = (const float*)d_in[3];  // [512,1,32,128]
  const int*   length = (const int*)d_in[4];    // [512]
  const float* alpha  = (const float*)d_in[5];  // scalar
  float* out = (float*)d_out;

  hipLaunchKernelGGL(zero_kernel, dim3(1), dim3(64), 0, stream, out);
  hipLaunchKernelGGL((loss_kernel<true>), dim3(512), dim3(256), 0, stream,
                     cf_low, attn, fore, length, alpha, out);
  hipLaunchKernelGGL((loss_kernel<false>), dim3(512), dim3(256), 0, stream,
                     cf_mid, attn, fore, length, alpha, out);
}

// Round 2
// 410.966 us; speedup vs baseline: 1.0056x; 1.0056x over previous
//
#include <hip/hip_runtime.h>
#include <stdint.h>

// ---------------------------------------------------------------------------
// Char segmentation loss — round 2.
// d_out: [0]=loss_low, [1]=loss_middle, [2..)=mask_low (512*27*1024 f32 0/1).
//
// R1 post-mortem: 512-block grid = 2 blocks/CU -> latency-bound at ~1 TB/s.
// R2: 5120-block fused main kernel (mid 8 slices/b + low 2 slices/b),
// per-(b,c) partials atomicAdd'd into d_ws, tiny prep/final kernels.
// ---------------------------------------------------------------------------

static __device__ __forceinline__ float wave_reduce_add(float v) {
  v += __shfl_xor(v, 1, 64);
  v += __shfl_xor(v, 2, 64);
  v += __shfl_xor(v, 4, 64);
  v += __shfl_xor(v, 8, 64);
  v += __shfl_xor(v, 16, 64);
  v += __shfl_xor(v, 32, 64);
  return v;
}

// Thresholded attention bits for one output column (src coord), replicating
// jax.image.resize half-pixel bilinear (antialias=False); edge == clamp.
// Frozen from R1 (absmax was 0.0) — do not touch the rounding.
static __device__ __forceinline__ uint32_t attn_bits(const float* sattn, float src,
                                                     int lens, float alpha) {
  const int k0 = (int)floorf(src);
  uint32_t bits = 0u;
  if (k0 < 0 || k0 >= 31) {
    const int kk = (k0 < 0) ? 0 : 31;
    for (int c = 0; c < 26; ++c) {
      float v = (c < lens) ? sattn[c * 32 + kk] : 0.0f;
      if (v > alpha) bits |= (1u << c);
    }
  } else {
    const float frac = src - (float)k0;  // exact (multiples of 1/8)
    const float w1 = frac, w0 = 1.0f - frac;
    for (int c = 0; c < 26; ++c) {
      // __f*_rn: forbid fma contraction so we bit-match the reference dot.
      float v = __fadd_rn(__fmul_rn(w0, sattn[c * 32 + k0]),
                          __fmul_rn(w1, sattn[c * 32 + k0 + 1]));
      v = (c < lens) ? v : 0.0f;
      if (v > alpha) bits |= (1u << c);
    }
  }
  return bits;
}

// Prep: per-(b,x) attention bits for both widths; zero the ws accumulators.
__global__ __launch_bounds__(192) void prep_kernel(
    const float* __restrict__ attn,   // [512,26,32]
    const int* __restrict__ length,   // [512]
    const float* __restrict__ alpha_p,
    uint32_t* __restrict__ bits_mid,  // [512,128]
    uint32_t* __restrict__ bits_low,  // [512,64]
    float* __restrict__ acc_mid,      // [512,81]
    float* __restrict__ acc_low,      // [512,81]
    float* __restrict__ ce) {         // [2]
  __shared__ float sattn[26 * 32];
  const int b = blockIdx.x;
  const int t = threadIdx.x;
  for (int i = t; i < 832; i += 192) sattn[i] = attn[b * 832 + i];
  if (t < 81) { acc_mid[b * 81 + t] = 0.0f; acc_low[b * 81 + t] = 0.0f; }
  if (b == 0 && t >= 96 && t < 98) ce[t - 96] = 0.0f;
  __syncthreads();
  const float alpha = alpha_p[0];
  const int lens = length[b] - 1;
  if (t < 128) {
    const float src = 0.25f * (float)t - 0.375f;  // 128 -> 32
    bits_mid[b * 128 + t] = attn_bits(sattn, src, lens, alpha);
  } else {
    const int x = t - 128;
    const float src = 0.5f * (float)x - 0.25f;    // 64 -> 32
    bits_low[b * 64 + x] = attn_bits(sattn, src, lens, alpha);
  }
}

// Main: blocks [0,4096) = mid slices (8 per b), [4096,5120) = low (2 per b).
// Each block: 512 pixels, full 27-channel softmax + dice partials.
__global__ __launch_bounds__(256) void main_kernel(
    const float* __restrict__ cf_mid,   // [512,27,4096]
    const float* __restrict__ cf_low,   // [512,27,1024]
    const float* __restrict__ fore,     // [512,4096]
    float* __restrict__ out,
    const uint32_t* __restrict__ bits_mid,
    const uint32_t* __restrict__ bits_low,
    float* __restrict__ acc_mid,
    float* __restrict__ acc_low,
    float* __restrict__ ce) {
  const int t = threadIdx.x;
  const int bid = blockIdx.x;
  const bool low = (bid >= 4096);
  int b, p0, W, HW;
  const float* cf;
  const uint32_t* bitsp;
  float* acc;
  if (low) {
    const int idx = bid - 4096;
    b = idx >> 1; p0 = (idx & 1) << 9; W = 64; HW = 1024;
    cf = cf_low; bitsp = bits_low + (size_t)b * 64; acc = acc_low;
  } else {
    b = bid >> 3; p0 = (bid & 7) << 9; W = 128; HW = 4096;
    cf = cf_mid; bitsp = bits_mid + (size_t)b * 128; acc = acc_mid;
  }
  const float* cfb = cf + (size_t)b * 27 * HW;
  const float* fb = fore + (size_t)b * 4096;
  float* mout = out + 2 + (size_t)b * 27 * 1024;  // low only

  float inter[27], s1[27], s2[27];
#pragma unroll
  for (int c = 0; c < 27; ++c) { inter[c] = 0.0f; s1[c] = 0.0f; s2[c] = 0.0f; }
  float cesum = 0.0f;

  for (int k = 0; k < 2; ++k) {
    const int p = p0 + t + (k << 8);
    const int x = p & (W - 1);

    int fmw;
    if (low) {
      // fm_low: exact 4-tap half-pixel average, frozen from R1.
      const int y = p >> 6;
      const float2* fr = (const float2*)(fb + (size_t)(2 * y) * 128 + 2 * x);
      const float2 f0 = fr[0];
      const float2 f1 = fr[64];
      const float t0 = __fadd_rn(0.5f * f0.x, 0.5f * f1.x);
      const float t1 = __fadd_rn(0.5f * f0.y, 0.5f * f1.y);
      const float fmv = __fadd_rn(0.5f * t0, 0.5f * t1);
      fmw = (fmv >= 0.4f) ? 1 : 0;
    } else {
      fmw = (fb[p] >= 0.4f) ? 1 : 0;
    }

    const uint32_t bits = bitsp[x];
    const int target = fmw ? (int)__ffs(bits) : 0;

    float l[27];
    float m = -1e30f, lt = 0.0f;
#pragma unroll
    for (int c = 0; c < 27; ++c) {
      const float v = cfb[(size_t)c * HW + p];
      l[c] = v;
      m = fmaxf(m, v);
      lt = (c == target) ? v : lt;
    }
    float s = 0.0f;
#pragma unroll
    for (int c = 0; c < 27; ++c) {
      const float e = __expf(l[c] - m);
      l[c] = e;
      s += e;
    }
    const float inv = 1.0f / s;
    cesum += (m + __logf(s) - lt);  // -log p(target)

#pragma unroll
    for (int c = 0; c < 27; ++c) {
      const float prob = l[c] * inv;
      s1[c] += prob;
      float mf;
      if (c == 0) mf = (float)(1 - fmw);
      else mf = (float)(((bits >> (c - 1)) & 1u) & (uint32_t)fmw);
      inter[c] += prob * mf;
      s2[c] += mf;
      if (low) mout[(size_t)c * 1024 + p] = mf;
    }
  }

  // wave butterfly + cross-wave LDS + one atomicAdd per (b,c,slot)
  __shared__ float red[4][82];
  const int wave = t >> 6, lane = t & 63;
#pragma unroll
  for (int c = 0; c < 27; ++c) {
    inter[c] = wave_reduce_add(inter[c]);
    s1[c] = wave_reduce_add(s1[c]);
    s2[c] = wave_reduce_add(s2[c]);
  }
  cesum = wave_reduce_add(cesum);
  if (lane == 0) {
#pragma unroll
    for (int c = 0; c < 27; ++c) {
      red[wave][c] = inter[c];
      red[wave][27 + c] = s1[c];
      red[wave][54 + c] = s2[c];
    }
    red[wave][81] = cesum;
  }
  __syncthreads();
  if (t < 82) {
    const float v = red[0][t] + red[1][t] + red[2][t] + red[3][t];
    if (t == 81) atomicAdd(&ce[low ? 0 : 1], v);
    else atomicAdd(&acc[(size_t)b * 81 + t], v);
  }
}

// Final: block 0 -> loss_low (out[0]), block 1 -> loss_middle (out[1]).
__global__ __launch_bounds__(256) void final_kernel(
    const float* __restrict__ acc_mid,
    const float* __restrict__ acc_low,
    const float* __restrict__ ce,
    const int* __restrict__ length,
    float* __restrict__ out) {
  const int B = blockIdx.x;  // 0=low, 1=mid
  const float* acc = (B == 0) ? acc_low : acc_mid;
  const float hw = (B == 0) ? 1024.0f : 4096.0f;
  const int t = threadIdx.x;
  float dsum = 0.0f;
  for (int b = t; b < 512; b += 256) {
    const int lens = length[b] - 1;
    const float* a = acc + (size_t)b * 81;
    float d = 0.0f;
    for (int c = 1; c < 27; ++c) {
      const float I = a[c], S1 = a[27 + c], S2 = a[54 + c];
      const float score = (2.0f * I + 1.0f) / (S1 + S2 + 1.0f);
      if (c <= lens) d += (1.0f - score);
    }
    dsum += d / (float)lens;
  }
  __shared__ float red[4];
  const int wave = t >> 6, lane = t & 63;
  dsum = wave_reduce_add(dsum);
  if (lane == 0) red[wave] = dsum;
  __syncthreads();
  if (t == 0) {
    const float dice = red[0] + red[1] + red[2] + red[3];
    out[B] = dice * (1.0f / 512.0f) + ce[B] * (1.0f / (512.0f * hw));
  }
}

extern "C" void kernel_launch(void* const* d_in, const int* in_sizes, int n_in,
                              void* d_out, int out_size, void* d_ws, size_t ws_size,
                              hipStream_t stream) {
  const float* cf_mid = (const float*)d_in[0];  // [512,27,32,128]
  const float* cf_low = (const float*)d_in[1];  // [512,27,16,64]
  const float* attn   = (const float*)d_in[2];  // [512,26,32]
  const float* fore   = (const float*)d_in[3];  // [512,1,32,128]
  const int*   length = (const int*)d_in[4];    // [512]
  const float* alpha  = (const float*)d_in[5];  // scalar
  float* out = (float*)d_out;

  // ws layout
  uint32_t* bits_mid = (uint32_t*)d_ws;                   // 512*128
  uint32_t* bits_low = bits_mid + 512 * 128;              // 512*64
  float* acc_mid = (float*)(bits_low + 512 * 64);         // 512*81
  float* acc_low = acc_mid + 512 * 81;                    // 512*81
  float* ce = acc_low + 512 * 81;                         // 2

  hipLaunchKernelGGL(prep_kernel, dim3(512), dim3(192), 0, stream,
                     attn, length, alpha, bits_mid, bits_low, acc_mid, acc_low, ce);
  hipLaunchKernelGGL(main_kernel, dim3(5120), dim3(256), 0, stream,
                     cf_mid, cf_low, fore, out, bits_mid, bits_low,
                     acc_mid, acc_low, ce);
  hipLaunchKernelGGL(final_kernel, dim3(2), dim3(256), 0, stream,
                     acc_mid, acc_low, ce, length, out);
}